// Round 15
// baseline (309.608 us; speedup 1.0000x reference)
//
#include <hip/hip_runtime.h>
#include <hip/hip_bf16.h>
#include <cstdint>
#include <cstddef>

#define N_NODES 50000
#define N_EDGES 640000
#define ET (N_EDGES + N_NODES)   // 690000 with self loops
#define IN_CH 128
#define H1 4
#define HC1 256                  // H1*C1
#define OUT_CH 64
#define SLOPE 0.2f
#define SCAN_NBLK ((N_NODES + 255) / 256)   // 196
#define XW (N_NODES * IN_CH / 8)            // 800000
#define W1N (IN_CH * HC1)                   // 32768
#define W2N (HC1 * OUT_CH)                  // 16384
#define CONVB ((XW + W1N + W2N + 255) / 256)  // 3317
#define EDGEB ((ET + 255) / 256)            // 2696
#define MT ((N_NODES + 63) / 64)            // 782
#define G1B (4 * MT)                        // 3128

typedef __attribute__((ext_vector_type(8))) short short8;
typedef __attribute__((ext_vector_type(4))) float floatx4;

__device__ __forceinline__ float bf2f(unsigned short u) {
    return __uint_as_float(((unsigned)u) << 16);
}
__device__ __forceinline__ unsigned short f2bf(float f) {
    unsigned u = __float_as_uint(f);
    unsigned r = 0x7fffu + ((u >> 16) & 1u);
    return (unsigned short)((u + r) >> 16);
}
__device__ __forceinline__ float ldf(const void* p, size_t i, bool f32) {
    return f32 ? ((const float*)p)[i] : bf2f(((const unsigned short*)p)[i]);
}

// ---------------- init: zero counts/state + detect dtype ----------------
__global__ __launch_bounds__(256) void init_all(
    const unsigned short* __restrict__ x, unsigned* __restrict__ flag,
    int* __restrict__ counts, int* __restrict__ state)
{
    int b = blockIdx.x;
    if (b < SCAN_NBLK) {
        int i = b * 256 + threadIdx.x;
        if (i < N_NODES) counts[i] = 0;
    } else {
        int t = threadIdx.x;
        if (t < 64) {
            int bad = 0;
            #pragma unroll
            for (int r = 0; r < 4; ++r) {
                float v = bf2f(x[r * 64 + t]);
                if (!(v == v) || fabsf(v) > 1e4f) bad = 1;
            }
            unsigned long long m = __ballot(bad != 0);
            if (t == 0) *flag = (m != 0ull) ? 1u : 0u;
        } else if (t == 64) {
            state[0] = 0; state[1] = 0;
        }
    }
}

// ---------------- count edges (FIRST: latency-bound) || conv (x, W1^T, W2^T) ---
__global__ __launch_bounds__(256) void conv_count(
    const void* __restrict__ x, const void* __restrict__ W1,
    const void* __restrict__ W2, const unsigned* __restrict__ flag,
    unsigned short* __restrict__ x16,
    unsigned short* __restrict__ Wt1, unsigned short* __restrict__ Wt2,
    const int* __restrict__ edst, int* __restrict__ counts)
{
    int b = blockIdx.x;
    if (b < EDGEB) {
        int i = b * 256 + threadIdx.x;
        if (i < ET) {
            int d = (i < N_EDGES) ? edst[i] : (i - N_EDGES);
            atomicAdd(&counts[d], 1);
        }
    } else {
        int i = (b - EDGEB) * 256 + threadIdx.x;
        const bool f32 = (*flag != 0);
        if (i < XW) {
            size_t off = (size_t)i * 8;
            uint4 st;
            if (f32) {
                const float* xp = (const float*)x + off;
                float4 a = *(const float4*)xp;
                float4 c = *(const float4*)(xp + 4);
                st.x = (unsigned)f2bf(a.x) | ((unsigned)f2bf(a.y) << 16);
                st.y = (unsigned)f2bf(a.z) | ((unsigned)f2bf(a.w) << 16);
                st.z = (unsigned)f2bf(c.x) | ((unsigned)f2bf(c.y) << 16);
                st.w = (unsigned)f2bf(c.z) | ((unsigned)f2bf(c.w) << 16);
            } else {
                st = *(const uint4*)((const unsigned short*)x + off);
            }
            *(uint4*)(x16 + off) = st;
        } else if (i < XW + W1N) {
            int j = i - XW;                       // Wt1[n][k] = W1[k][n]
            int n = j / IN_CH, k = j % IN_CH;
            Wt1[j] = f2bf(ldf(W1, (size_t)k * HC1 + n, f32));
        } else if (i < XW + W1N + W2N) {
            int j = i - XW - W1N;                 // Wt2[n][k] = W2[k][n]
            int n = j / HC1, k = j % HC1;
            Wt2[j] = f2bf(ldf(W2, (size_t)k * OUT_CH + n, f32));
        }
    }
}

// ---------------- single-dispatch two-phase scan ----------------
__global__ __launch_bounds__(256) void scan_onepass(
    const int* __restrict__ counts, int* __restrict__ rowptr,
    int* __restrict__ cursor, int* __restrict__ bsum,
    int* __restrict__ boff, int* __restrict__ state)
{
    __shared__ int s[256];
    const int t = threadIdx.x, b = blockIdx.x;
    const int i = b * 256 + t;
    int v = (i < N_NODES) ? counts[i] : 0;
    s[t] = v;
    __syncthreads();
    #pragma unroll
    for (int off = 1; off < 256; off <<= 1) {
        int u = (t >= off) ? s[t - off] : 0;
        __syncthreads();
        s[t] += u;
        __syncthreads();
    }
    const int incl = s[t];
    if (t == 255) {
        __hip_atomic_store(&bsum[b], incl, __ATOMIC_RELAXED, __HIP_MEMORY_SCOPE_AGENT);
        __hip_atomic_fetch_add(&state[0], 1, __ATOMIC_ACQ_REL, __HIP_MEMORY_SCOPE_AGENT);
    }
    if (b == 0) {
        if (t == 0) {
            while (__hip_atomic_load(&state[0], __ATOMIC_ACQUIRE, __HIP_MEMORY_SCOPE_AGENT) < SCAN_NBLK)
                __builtin_amdgcn_s_sleep(8);
        }
        __syncthreads();
        int w = (t < SCAN_NBLK)
              ? __hip_atomic_load(&bsum[t], __ATOMIC_RELAXED, __HIP_MEMORY_SCOPE_AGENT) : 0;
        s[t] = w;
        __syncthreads();
        #pragma unroll
        for (int off = 1; off < 256; off <<= 1) {
            int u = (t >= off) ? s[t - off] : 0;
            __syncthreads();
            s[t] += u;
            __syncthreads();
        }
        if (t < SCAN_NBLK)
            __hip_atomic_store(&boff[t], s[t] - w, __ATOMIC_RELAXED, __HIP_MEMORY_SCOPE_AGENT);
        __syncthreads();
        if (t == 0)
            __hip_atomic_store(&state[1], 1, __ATOMIC_RELEASE, __HIP_MEMORY_SCOPE_AGENT);
    }
    if (t == 0) {
        while (__hip_atomic_load(&state[1], __ATOMIC_ACQUIRE, __HIP_MEMORY_SCOPE_AGENT) == 0)
            __builtin_amdgcn_s_sleep(8);
    }
    __syncthreads();
    int off0 = __hip_atomic_load(&boff[b], __ATOMIC_RELAXED, __HIP_MEMORY_SCOPE_AGENT);
    if (i < N_NODES) {
        int r = off0 + incl - v;
        rowptr[i] = r; cursor[i] = r;
    }
    if (i == 0) rowptr[N_NODES] = ET;
}

// ---------------- MFMA bf16 GEMM body (round-12 proven: simple K-loop) --------
template <int KK>
__device__ __forceinline__ void gemm_body(
    const unsigned short* __restrict__ A, const unsigned short* __restrict__ Bt,
    const void* __restrict__ avs, const void* __restrict__ avd,
    const unsigned* __restrict__ flag, unsigned short* __restrict__ C,
    float* __restrict__ als, float* __restrict__ ald,
    int M, int N, int bx, int by)
{
    const int tid = threadIdx.x;
    const int m0 = by * 64, n0 = bx * 64;
    const int w = tid >> 6, lane = tid & 63;
    const int ln = lane & 15, quad = lane >> 4;
    const int m_frag = m0 + w * 16 + ln;
    floatx4 acc[4] = {{0.f,0.f,0.f,0.f},{0.f,0.f,0.f,0.f},{0.f,0.f,0.f,0.f},{0.f,0.f,0.f,0.f}};

    #pragma unroll
    for (int ks = 0; ks < KK / 32; ++ks) {
        const int kbase = ks * 32 + quad * 8;
        short8 a;
        if (m_frag < M) {
            a = *(const short8*)(A + (size_t)m_frag * KK + kbase);
        } else {
            #pragma unroll
            for (int j = 0; j < 8; ++j) a[j] = 0;
        }
        #pragma unroll
        for (int sub = 0; sub < 4; ++sub) {
            short8 b = *(const short8*)(Bt + (size_t)(n0 + sub * 16 + ln) * KK + kbase);
            acc[sub] = __builtin_amdgcn_mfma_f32_16x16x32_bf16(a, b, acc[sub], 0, 0, 0);
        }
    }

    #pragma unroll
    for (int sub = 0; sub < 4; ++sub) {
        #pragma unroll
        for (int r = 0; r < 4; ++r) {
            int m = m0 + w * 16 + quad * 4 + r;
            if (m < M)
                C[(size_t)m * N + n0 + sub * 16 + ln] = f2bf(acc[sub][r]);
        }
    }

    const bool f32in = (*flag != 0);
    float as[4], av[4];
    #pragma unroll
    for (int sub = 0; sub < 4; ++sub) {
        as[sub] = ldf(avs, n0 + sub * 16 + ln, f32in);
        av[sub] = ldf(avd, n0 + sub * 16 + ln, f32in);
    }
    const int Hh = N >> 6;
    #pragma unroll
    for (int r = 0; r < 4; ++r) {
        float ps = 0.f, pd = 0.f;
        #pragma unroll
        for (int sub = 0; sub < 4; ++sub) {
            ps += acc[sub][r] * as[sub];
            pd += acc[sub][r] * av[sub];
        }
        #pragma unroll
        for (int off = 1; off < 16; off <<= 1) {
            ps += __shfl_xor(ps, off, 64);
            pd += __shfl_xor(pd, off, 64);
        }
        int m = m0 + w * 16 + quad * 4 + r;
        if (ln == 0 && m < M) {
            als[(size_t)m * Hh + bx] = ps;
            ald[(size_t)m * Hh + bx] = pd;
        }
    }
}

// ---------------- fill_csr (FIRST: latency-bound) || layer-1 GEMM ----------
__global__ __launch_bounds__(256) void gemm1_fill(
    const unsigned short* __restrict__ x16, const unsigned short* __restrict__ Wt1,
    const void* __restrict__ as1, const void* __restrict__ ad1,
    const unsigned* __restrict__ flag, unsigned short* __restrict__ h16,
    float* __restrict__ als, float* __restrict__ ald,
    const int* __restrict__ esrc, const int* __restrict__ edst,
    int* __restrict__ cursor, int* __restrict__ ecsr)
{
    int b = blockIdx.x;
    if (b < EDGEB) {
        int i = b * 256 + threadIdx.x;
        if (i < ET) {
            int s = (i < N_EDGES) ? esrc[i] : (i - N_EDGES);
            int d = (i < N_EDGES) ? edst[i] : (i - N_EDGES);
            int pos = atomicAdd(&cursor[d], 1);
            ecsr[pos] = s;
        }
    } else {
        int g = b - EDGEB;
        gemm_body<IN_CH>(x16, Wt1, as1, ad1, flag, h16, als, ald,
                         N_NODES, HC1, g & 3, g >> 2);
    }
}

// ---------------- layer-2 GEMM ----------------
__global__ __launch_bounds__(256) void gemm2(
    const unsigned short* __restrict__ xo16, const unsigned short* __restrict__ Wt2,
    const void* __restrict__ as2, const void* __restrict__ ad2,
    const unsigned* __restrict__ flag, unsigned short* __restrict__ h2,
    float* __restrict__ als, float* __restrict__ ald)
{
    gemm_body<HC1>(xo16, Wt2, as2, ad2, flag, h2, als, ald,
                   N_NODES, OUT_CH, 0, blockIdx.x);
}

// ---------------- fused softmax + gather-aggregate, layer 1 (H=4) ----------------
// One wave per dst. Lane l: head l>>4, channels (l&15)*4..+3. 4-edge unroll + tail,
// with NEXT-batch ecsr prefetch pipelined past the current batch's gathers.
__global__ __launch_bounds__(256) void agg_node1(
    const int* __restrict__ rowptr, const int* __restrict__ ecsr,
    const unsigned short* __restrict__ h, const float* __restrict__ als,
    const float* __restrict__ ald, const void* __restrict__ bias,
    const unsigned* __restrict__ flag, unsigned short* __restrict__ out)
{
    int wave = (blockIdx.x * blockDim.x + threadIdx.x) >> 6;
    int lane = threadIdx.x & 63;
    if (wave >= N_NODES) return;
    const int d = wave;
    const int hg = lane >> 4;          // head
    const int c0 = (lane & 15) << 2;   // channel base
    const int lo = rowptr[d], hi = rowptr[d + 1];
    const float ad = ald[d * H1 + hg];

    float acc0 = 0.f, acc1 = 0.f, acc2 = 0.f, acc3 = 0.f, den = 0.f;

    int e = lo;
    int ns0 = 0, ns1 = 0, ns2 = 0, ns3 = 0;
    if (e + 3 < hi) { ns0 = ecsr[e]; ns1 = ecsr[e+1]; ns2 = ecsr[e+2]; ns3 = ecsr[e+3]; }
    for (; e + 3 < hi; e += 4) {
        int s0 = ns0, s1 = ns1, s2 = ns2, s3 = ns3;
        int e2 = e + 4;
        if (e2 + 3 < hi) {   // prefetch next batch's indices before gather wait
            ns0 = ecsr[e2]; ns1 = ecsr[e2+1]; ns2 = ecsr[e2+2]; ns3 = ecsr[e2+3];
        }
        uint2 q0 = *(const uint2*)(h + (size_t)s0 * HC1 + hg * 64 + c0);
        uint2 q1 = *(const uint2*)(h + (size_t)s1 * HC1 + hg * 64 + c0);
        uint2 q2 = *(const uint2*)(h + (size_t)s2 * HC1 + hg * 64 + c0);
        uint2 q3 = *(const uint2*)(h + (size_t)s3 * HC1 + hg * 64 + c0);
        float t0 = als[s0 * H1 + hg] + ad;
        float t1 = als[s1 * H1 + hg] + ad;
        float t2 = als[s2 * H1 + hg] + ad;
        float t3 = als[s3 * H1 + hg] + ad;
        t0 = (t0 > 0.f) ? t0 : SLOPE * t0;
        t1 = (t1 > 0.f) ? t1 : SLOPE * t1;
        t2 = (t2 > 0.f) ? t2 : SLOPE * t2;
        t3 = (t3 > 0.f) ? t3 : SLOPE * t3;
        float p0 = __expf(t0), p1 = __expf(t1), p2 = __expf(t2), p3 = __expf(t3);
        den += (p0 + p1) + (p2 + p3);
        acc0 += p0 * __uint_as_float(q0.x << 16)         + p1 * __uint_as_float(q1.x << 16)
              + p2 * __uint_as_float(q2.x << 16)         + p3 * __uint_as_float(q3.x << 16);
        acc1 += p0 * __uint_as_float(q0.x & 0xffff0000u) + p1 * __uint_as_float(q1.x & 0xffff0000u)
              + p2 * __uint_as_float(q2.x & 0xffff0000u) + p3 * __uint_as_float(q3.x & 0xffff0000u);
        acc2 += p0 * __uint_as_float(q0.y << 16)         + p1 * __uint_as_float(q1.y << 16)
              + p2 * __uint_as_float(q2.y << 16)         + p3 * __uint_as_float(q3.y << 16);
        acc3 += p0 * __uint_as_float(q0.y & 0xffff0000u) + p1 * __uint_as_float(q1.y & 0xffff0000u)
              + p2 * __uint_as_float(q2.y & 0xffff0000u) + p3 * __uint_as_float(q3.y & 0xffff0000u);
    }
    for (; e < hi; ++e) {
        int s0 = ecsr[e];
        uint2 q0 = *(const uint2*)(h + (size_t)s0 * HC1 + hg * 64 + c0);
        float t0 = als[s0 * H1 + hg] + ad;
        t0 = (t0 > 0.f) ? t0 : SLOPE * t0;
        float p0 = __expf(t0);
        den += p0;
        acc0 += p0 * __uint_as_float(q0.x << 16);
        acc1 += p0 * __uint_as_float(q0.x & 0xffff0000u);
        acc2 += p0 * __uint_as_float(q0.y << 16);
        acc3 += p0 * __uint_as_float(q0.y & 0xffff0000u);
    }

    const bool f32in = (*flag != 0);
    const float inv = 1.f / den;
    float v0 = acc0 * inv + ldf(bias, hg * 64 + c0 + 0, f32in);
    float v1 = acc1 * inv + ldf(bias, hg * 64 + c0 + 1, f32in);
    float v2 = acc2 * inv + ldf(bias, hg * 64 + c0 + 2, f32in);
    float v3 = acc3 * inv + ldf(bias, hg * 64 + c0 + 3, f32in);
    v0 = (v0 > 0.f) ? v0 : (__expf(v0) - 1.f);
    v1 = (v1 > 0.f) ? v1 : (__expf(v1) - 1.f);
    v2 = (v2 > 0.f) ? v2 : (__expf(v2) - 1.f);
    v3 = (v3 > 0.f) ? v3 : (__expf(v3) - 1.f);
    uint2 st;
    st.x = (unsigned)f2bf(v0) | ((unsigned)f2bf(v1) << 16);
    st.y = (unsigned)f2bf(v2) | ((unsigned)f2bf(v3) << 16);
    *(uint2*)(out + (size_t)d * HC1 + hg * 64 + c0) = st;
}

// ---------------- fused softmax + gather-aggregate, layer 2 (H=1) ----------------
__global__ __launch_bounds__(256) void agg_node2(
    const int* __restrict__ rowptr, const int* __restrict__ ecsr,
    const unsigned short* __restrict__ h, const float* __restrict__ als,
    const float* __restrict__ ald, const void* __restrict__ bias,
    const unsigned* __restrict__ flag, float* __restrict__ out)
{
    int wave = (blockIdx.x * blockDim.x + threadIdx.x) >> 6;
    int lane = threadIdx.x & 63;
    if (wave >= N_NODES) return;
    const int d = wave;
    const int eg = lane >> 3;          // edge slot 0..7
    const int c0 = (lane & 7) << 3;    // channel base (8 channels)
    const int lo = rowptr[d], hi = rowptr[d + 1];
    const float ad = ald[d];

    float acc[8];
    #pragma unroll
    for (int j = 0; j < 8; ++j) acc[j] = 0.f;
    float den = 0.f;

    for (int eb = lo; eb < hi; eb += 8) {
        int e = eb + eg;
        if (e < hi) {
            int s = ecsr[e];
            uint4 q = *(const uint4*)(h + (size_t)s * OUT_CH + c0);
            float t = als[s] + ad;
            t = (t > 0.f) ? t : SLOPE * t;
            float p = __expf(t);
            den += p;
            acc[0] += p * __uint_as_float(q.x << 16);
            acc[1] += p * __uint_as_float(q.x & 0xffff0000u);
            acc[2] += p * __uint_as_float(q.y << 16);
            acc[3] += p * __uint_as_float(q.y & 0xffff0000u);
            acc[4] += p * __uint_as_float(q.z << 16);
            acc[5] += p * __uint_as_float(q.z & 0xffff0000u);
            acc[6] += p * __uint_as_float(q.w << 16);
            acc[7] += p * __uint_as_float(q.w & 0xffff0000u);
        }
    }
    #pragma unroll
    for (int off = 8; off <= 32; off <<= 1) {
        den += __shfl_xor(den, off, 64);
        #pragma unroll
        for (int j = 0; j < 8; ++j) acc[j] += __shfl_xor(acc[j], off, 64);
    }
    if (lane < 8) {
        const bool f32in = (*flag != 0);
        const float inv = 1.f / den;
        float4 v0, v1;
        v0.x = acc[0] * inv + ldf(bias, c0 + 0, f32in);
        v0.y = acc[1] * inv + ldf(bias, c0 + 1, f32in);
        v0.z = acc[2] * inv + ldf(bias, c0 + 2, f32in);
        v0.w = acc[3] * inv + ldf(bias, c0 + 3, f32in);
        v1.x = acc[4] * inv + ldf(bias, c0 + 4, f32in);
        v1.y = acc[5] * inv + ldf(bias, c0 + 5, f32in);
        v1.z = acc[6] * inv + ldf(bias, c0 + 6, f32in);
        v1.w = acc[7] * inv + ldf(bias, c0 + 7, f32in);
        *(float4*)(out + (size_t)d * OUT_CH + c0) = v0;
        *(float4*)(out + (size_t)d * OUT_CH + c0 + 4) = v1;
    }
}

extern "C" void kernel_launch(void* const* d_in, const int* in_sizes, int n_in,
                              void* d_out, int out_size, void* d_ws, size_t ws_size,
                              hipStream_t stream)
{
    const void* x   = d_in[0];
    const void* W1  = d_in[1];
    const void* as1 = d_in[2];
    const void* ad1 = d_in[3];
    const void* b1  = d_in[4];
    const void* W2  = d_in[5];
    const void* as2 = d_in[6];
    const void* ad2 = d_in[7];
    const void* b2  = d_in[8];
    const int* esrc = (const int*)d_in[9];
    const int* edst = (const int*)d_in[10];
    float* out = (float*)d_out;  // [N,64] float32

    char* base = (char*)d_ws;
    const size_t MB = 1024 * 1024;
    unsigned short* x16  = (unsigned short*)(base);            // 12.8 MB [N,128] bf16
    unsigned short* h16  = (unsigned short*)(base + 13 * MB);  // 25.6 MB h1 [N,256] bf16
    unsigned short* xo16 = (unsigned short*)(base + 39 * MB);  // 25.6 MB x2 [N,256] bf16
    unsigned short* h2   = (unsigned short*)(base + 65 * MB);  //  6.4 MB h2 [N,64] bf16
    float* als    = (float*)(base + 72 * MB);
    float* ald    = (float*)(base + 73 * MB);
    unsigned short* Wt1 = (unsigned short*)(base + 74 * MB);   // 64 KB [256][128]
    unsigned short* Wt2 = (unsigned short*)(base + 75 * MB);   // 32 KB [64][256]
    int* counts   = (int*)(base + 76 * MB);
    int* rowptr   = (int*)(base + 77 * MB);
    int* cursor   = (int*)(base + 78 * MB);
    int* ecsr     = (int*)(base + 79 * MB);                    //  2.8 MB
    int* bsum     = (int*)(base + 82 * MB);                    //  196 ints
    int* boff     = bsum + 256;
    int* state    = boff + 256;                                //  2 ints
    unsigned* flag = (unsigned*)(base + 83 * MB);

    const int BLK = 256;
    const int node_wave_blocks = (N_NODES * 64 + BLK - 1) / BLK;  // 12500

    // 1. init: zero counts/state + detect dtype
    init_all<<<SCAN_NBLK + 1, BLK, 0, stream>>>(
        (const unsigned short*)x, flag, counts, state);

    // 2. count edges (first) || conv (x16, Wt1, Wt2)
    conv_count<<<CONVB + EDGEB, BLK, 0, stream>>>(
        x, W1, W2, flag, x16, Wt1, Wt2, edst, counts);

    // 3. single-dispatch scan -> rowptr, cursor
    scan_onepass<<<SCAN_NBLK, BLK, 0, stream>>>(
        counts, rowptr, cursor, bsum, boff, state);

    // 4. fill_csr (first) || layer-1 GEMM
    gemm1_fill<<<G1B + EDGEB, BLK, 0, stream>>>(
        x16, Wt1, as1, ad1, flag, h16, als, ald, esrc, edst, cursor, ecsr);

    // 5. layer-1 aggregate
    agg_node1<<<node_wave_blocks, BLK, 0, stream>>>(
        rowptr, ecsr, h16, als, ald, b1, flag, xo16);

    // 6. layer-2 GEMM
    gemm2<<<MT, BLK, 0, stream>>>(xo16, Wt2, as2, ad2, flag, h2, als, ald);

    // 7. layer-2 aggregate -> out
    agg_node2<<<node_wave_blocks, BLK, 0, stream>>>(
        rowptr, ecsr, h2, als, ald, b2, flag, out);
}

// Round 16
// 286.109 us; speedup vs baseline: 1.0821x; 1.0821x over previous
//
#include <hip/hip_runtime.h>
#include <hip/hip_bf16.h>
#include <cstdint>
#include <cstddef>

#define N_NODES 50000
#define N_EDGES 640000
#define ET (N_EDGES + N_NODES)   // 690000 with self loops
#define IN_CH 128
#define H1 4
#define HC1 256                  // H1*C1
#define OUT_CH 64
#define SLOPE 0.2f
#define SCAN_NBLK ((N_NODES + 255) / 256)   // 196
#define XW (N_NODES * IN_CH / 8)            // 800000
#define W1N (IN_CH * HC1)                   // 32768
#define W2N (HC1 * OUT_CH)                  // 16384
#define CONVB ((XW + W1N + W2N + 255) / 256)  // 3317
#define EDGEB ((ET + 255) / 256)            // 2696
#define MT ((N_NODES + 63) / 64)            // 782
#define G1B (4 * MT)                        // 3128

typedef __attribute__((ext_vector_type(8))) short short8;
typedef __attribute__((ext_vector_type(4))) float floatx4;

__device__ __forceinline__ float bf2f(unsigned short u) {
    return __uint_as_float(((unsigned)u) << 16);
}
__device__ __forceinline__ unsigned short f2bf(float f) {
    unsigned u = __float_as_uint(f);
    unsigned r = 0x7fffu + ((u >> 16) & 1u);
    return (unsigned short)((u + r) >> 16);
}
__device__ __forceinline__ float ldf(const void* p, size_t i, bool f32) {
    return f32 ? ((const float*)p)[i] : bf2f(((const unsigned short*)p)[i]);
}

// ---------------- init: zero counts/state + detect dtype ----------------
__global__ __launch_bounds__(256) void init_all(
    const unsigned short* __restrict__ x, unsigned* __restrict__ flag,
    int* __restrict__ counts, int* __restrict__ state)
{
    int b = blockIdx.x;
    if (b < SCAN_NBLK) {
        int i = b * 256 + threadIdx.x;
        if (i < N_NODES) counts[i] = 0;
    } else {
        int t = threadIdx.x;
        if (t < 64) {
            int bad = 0;
            #pragma unroll
            for (int r = 0; r < 4; ++r) {
                float v = bf2f(x[r * 64 + t]);
                if (!(v == v) || fabsf(v) > 1e4f) bad = 1;
            }
            unsigned long long m = __ballot(bad != 0);
            if (t == 0) *flag = (m != 0ull) ? 1u : 0u;
        } else if (t == 64) {
            state[0] = 0; state[1] = 0;
        }
    }
}

// ---------------- conv (x->bf16, W1^T, W2^T) || count edges (+record slot) ----
__global__ __launch_bounds__(256) void conv_count(
    const void* __restrict__ x, const void* __restrict__ W1,
    const void* __restrict__ W2, const unsigned* __restrict__ flag,
    unsigned short* __restrict__ x16,
    unsigned short* __restrict__ Wt1, unsigned short* __restrict__ Wt2,
    const int* __restrict__ edst, int* __restrict__ counts,
    int* __restrict__ epos)
{
    int b = blockIdx.x;
    if (b < CONVB) {
        int i = b * 256 + threadIdx.x;
        const bool f32 = (*flag != 0);
        if (i < XW) {
            size_t off = (size_t)i * 8;
            uint4 st;
            if (f32) {
                const float* xp = (const float*)x + off;
                float4 a = *(const float4*)xp;
                float4 c = *(const float4*)(xp + 4);
                st.x = (unsigned)f2bf(a.x) | ((unsigned)f2bf(a.y) << 16);
                st.y = (unsigned)f2bf(a.z) | ((unsigned)f2bf(a.w) << 16);
                st.z = (unsigned)f2bf(c.x) | ((unsigned)f2bf(c.y) << 16);
                st.w = (unsigned)f2bf(c.z) | ((unsigned)f2bf(c.w) << 16);
            } else {
                st = *(const uint4*)((const unsigned short*)x + off);
            }
            *(uint4*)(x16 + off) = st;
        } else if (i < XW + W1N) {
            int j = i - XW;                       // Wt1[n][k] = W1[k][n]
            int n = j / IN_CH, k = j % IN_CH;
            Wt1[j] = f2bf(ldf(W1, (size_t)k * HC1 + n, f32));
        } else if (i < XW + W1N + W2N) {
            int j = i - XW - W1N;                 // Wt2[n][k] = W2[k][n]
            int n = j / HC1, k = j % HC1;
            Wt2[j] = f2bf(ldf(W2, (size_t)k * OUT_CH + n, f32));
        }
    } else {
        int i = (b - CONVB) * 256 + threadIdx.x;
        if (i < ET) {
            int d = (i < N_EDGES) ? edst[i] : (i - N_EDGES);
            // the atomic's return value IS the within-bucket slot: record it so
            // the fill pass needs no atomic at all.
            epos[i] = atomicAdd(&counts[d], 1);
        }
    }
}

// ---------------- single-dispatch two-phase scan ----------------
__global__ __launch_bounds__(256) void scan_onepass(
    const int* __restrict__ counts, int* __restrict__ rowptr,
    int* __restrict__ bsum, int* __restrict__ boff, int* __restrict__ state)
{
    __shared__ int s[256];
    const int t = threadIdx.x, b = blockIdx.x;
    const int i = b * 256 + t;
    int v = (i < N_NODES) ? counts[i] : 0;
    s[t] = v;
    __syncthreads();
    #pragma unroll
    for (int off = 1; off < 256; off <<= 1) {
        int u = (t >= off) ? s[t - off] : 0;
        __syncthreads();
        s[t] += u;
        __syncthreads();
    }
    const int incl = s[t];
    if (t == 255) {
        __hip_atomic_store(&bsum[b], incl, __ATOMIC_RELAXED, __HIP_MEMORY_SCOPE_AGENT);
        __hip_atomic_fetch_add(&state[0], 1, __ATOMIC_ACQ_REL, __HIP_MEMORY_SCOPE_AGENT);
    }
    if (b == 0) {
        if (t == 0) {
            while (__hip_atomic_load(&state[0], __ATOMIC_ACQUIRE, __HIP_MEMORY_SCOPE_AGENT) < SCAN_NBLK)
                __builtin_amdgcn_s_sleep(8);
        }
        __syncthreads();
        int w = (t < SCAN_NBLK)
              ? __hip_atomic_load(&bsum[t], __ATOMIC_RELAXED, __HIP_MEMORY_SCOPE_AGENT) : 0;
        s[t] = w;
        __syncthreads();
        #pragma unroll
        for (int off = 1; off < 256; off <<= 1) {
            int u = (t >= off) ? s[t - off] : 0;
            __syncthreads();
            s[t] += u;
            __syncthreads();
        }
        if (t < SCAN_NBLK)
            __hip_atomic_store(&boff[t], s[t] - w, __ATOMIC_RELAXED, __HIP_MEMORY_SCOPE_AGENT);
        __syncthreads();
        if (t == 0)
            __hip_atomic_store(&state[1], 1, __ATOMIC_RELEASE, __HIP_MEMORY_SCOPE_AGENT);
    }
    if (t == 0) {
        while (__hip_atomic_load(&state[1], __ATOMIC_ACQUIRE, __HIP_MEMORY_SCOPE_AGENT) == 0)
            __builtin_amdgcn_s_sleep(8);
    }
    __syncthreads();
    int off0 = __hip_atomic_load(&boff[b], __ATOMIC_RELAXED, __HIP_MEMORY_SCOPE_AGENT);
    if (i < N_NODES)
        rowptr[i] = off0 + incl - v;   // exclusive
    if (i == 0) rowptr[N_NODES] = ET;
}

// ---------------- MFMA bf16 GEMM body (round-12 proven: simple K-loop) --------
template <int KK>
__device__ __forceinline__ void gemm_body(
    const unsigned short* __restrict__ A, const unsigned short* __restrict__ Bt,
    const void* __restrict__ avs, const void* __restrict__ avd,
    const unsigned* __restrict__ flag, unsigned short* __restrict__ C,
    float* __restrict__ als, float* __restrict__ ald,
    int M, int N, int bx, int by)
{
    const int tid = threadIdx.x;
    const int m0 = by * 64, n0 = bx * 64;
    const int w = tid >> 6, lane = tid & 63;
    const int ln = lane & 15, quad = lane >> 4;
    const int m_frag = m0 + w * 16 + ln;
    floatx4 acc[4] = {{0.f,0.f,0.f,0.f},{0.f,0.f,0.f,0.f},{0.f,0.f,0.f,0.f},{0.f,0.f,0.f,0.f}};

    #pragma unroll
    for (int ks = 0; ks < KK / 32; ++ks) {
        const int kbase = ks * 32 + quad * 8;
        short8 a;
        if (m_frag < M) {
            a = *(const short8*)(A + (size_t)m_frag * KK + kbase);
        } else {
            #pragma unroll
            for (int j = 0; j < 8; ++j) a[j] = 0;
        }
        #pragma unroll
        for (int sub = 0; sub < 4; ++sub) {
            short8 b = *(const short8*)(Bt + (size_t)(n0 + sub * 16 + ln) * KK + kbase);
            acc[sub] = __builtin_amdgcn_mfma_f32_16x16x32_bf16(a, b, acc[sub], 0, 0, 0);
        }
    }

    #pragma unroll
    for (int sub = 0; sub < 4; ++sub) {
        #pragma unroll
        for (int r = 0; r < 4; ++r) {
            int m = m0 + w * 16 + quad * 4 + r;
            if (m < M)
                C[(size_t)m * N + n0 + sub * 16 + ln] = f2bf(acc[sub][r]);
        }
    }

    const bool f32in = (*flag != 0);
    float as[4], av[4];
    #pragma unroll
    for (int sub = 0; sub < 4; ++sub) {
        as[sub] = ldf(avs, n0 + sub * 16 + ln, f32in);
        av[sub] = ldf(avd, n0 + sub * 16 + ln, f32in);
    }
    const int Hh = N >> 6;
    #pragma unroll
    for (int r = 0; r < 4; ++r) {
        float ps = 0.f, pd = 0.f;
        #pragma unroll
        for (int sub = 0; sub < 4; ++sub) {
            ps += acc[sub][r] * as[sub];
            pd += acc[sub][r] * av[sub];
        }
        #pragma unroll
        for (int off = 1; off < 16; off <<= 1) {
            ps += __shfl_xor(ps, off, 64);
            pd += __shfl_xor(pd, off, 64);
        }
        int m = m0 + w * 16 + quad * 4 + r;
        if (ln == 0 && m < M) {
            als[(size_t)m * Hh + bx] = ps;
            ald[(size_t)m * Hh + bx] = pd;
        }
    }
}

// ---------------- layer-1 GEMM || fill_csr (atomic-free) ----------
__global__ __launch_bounds__(256) void gemm1_fill(
    const unsigned short* __restrict__ x16, const unsigned short* __restrict__ Wt1,
    const void* __restrict__ as1, const void* __restrict__ ad1,
    const unsigned* __restrict__ flag, unsigned short* __restrict__ h16,
    float* __restrict__ als, float* __restrict__ ald,
    const int* __restrict__ esrc, const int* __restrict__ edst,
    const int* __restrict__ rowptr, const int* __restrict__ epos,
    int* __restrict__ ecsr)
{
    int b = blockIdx.x;
    if (b < G1B) {
        gemm_body<IN_CH>(x16, Wt1, as1, ad1, flag, h16, als, ald,
                         N_NODES, HC1, b & 3, b >> 2);
    } else {
        int i = (b - G1B) * 256 + threadIdx.x;
        if (i < ET) {
            int s = (i < N_EDGES) ? esrc[i] : (i - N_EDGES);
            int d = (i < N_EDGES) ? edst[i] : (i - N_EDGES);
            ecsr[rowptr[d] + epos[i]] = s;   // no atomic: slot was recorded in count
        }
    }
}

// ---------------- layer-2 GEMM ----------------
__global__ __launch_bounds__(256) void gemm2(
    const unsigned short* __restrict__ xo16, const unsigned short* __restrict__ Wt2,
    const void* __restrict__ as2, const void* __restrict__ ad2,
    const unsigned* __restrict__ flag, unsigned short* __restrict__ h2,
    float* __restrict__ als, float* __restrict__ ald)
{
    gemm_body<HC1>(xo16, Wt2, as2, ad2, flag, h2, als, ald,
                   N_NODES, OUT_CH, 0, blockIdx.x);
}

// ---------------- fused softmax + gather-aggregate, layer 1 (H=4) ----------------
__global__ __launch_bounds__(256) void agg_node1(
    const int* __restrict__ rowptr, const int* __restrict__ ecsr,
    const unsigned short* __restrict__ h, const float* __restrict__ als,
    const float* __restrict__ ald, const void* __restrict__ bias,
    const unsigned* __restrict__ flag, unsigned short* __restrict__ out)
{
    int wave = (blockIdx.x * blockDim.x + threadIdx.x) >> 6;
    int lane = threadIdx.x & 63;
    if (wave >= N_NODES) return;
    const int d = wave;
    const int hg = lane >> 4;          // head
    const int c0 = (lane & 15) << 2;   // channel base
    const int lo = rowptr[d], hi = rowptr[d + 1];
    const float ad = ald[d * H1 + hg];

    float acc0 = 0.f, acc1 = 0.f, acc2 = 0.f, acc3 = 0.f, den = 0.f;

    int e = lo;
    for (; e + 3 < hi; e += 4) {
        int s0 = ecsr[e], s1 = ecsr[e + 1], s2 = ecsr[e + 2], s3 = ecsr[e + 3];
        uint2 q0 = *(const uint2*)(h + (size_t)s0 * HC1 + hg * 64 + c0);
        uint2 q1 = *(const uint2*)(h + (size_t)s1 * HC1 + hg * 64 + c0);
        uint2 q2 = *(const uint2*)(h + (size_t)s2 * HC1 + hg * 64 + c0);
        uint2 q3 = *(const uint2*)(h + (size_t)s3 * HC1 + hg * 64 + c0);
        float t0 = als[s0 * H1 + hg] + ad;
        float t1 = als[s1 * H1 + hg] + ad;
        float t2 = als[s2 * H1 + hg] + ad;
        float t3 = als[s3 * H1 + hg] + ad;
        t0 = (t0 > 0.f) ? t0 : SLOPE * t0;
        t1 = (t1 > 0.f) ? t1 : SLOPE * t1;
        t2 = (t2 > 0.f) ? t2 : SLOPE * t2;
        t3 = (t3 > 0.f) ? t3 : SLOPE * t3;
        float p0 = __expf(t0), p1 = __expf(t1), p2 = __expf(t2), p3 = __expf(t3);
        den += (p0 + p1) + (p2 + p3);
        acc0 += p0 * __uint_as_float(q0.x << 16)         + p1 * __uint_as_float(q1.x << 16)
              + p2 * __uint_as_float(q2.x << 16)         + p3 * __uint_as_float(q3.x << 16);
        acc1 += p0 * __uint_as_float(q0.x & 0xffff0000u) + p1 * __uint_as_float(q1.x & 0xffff0000u)
              + p2 * __uint_as_float(q2.x & 0xffff0000u) + p3 * __uint_as_float(q3.x & 0xffff0000u);
        acc2 += p0 * __uint_as_float(q0.y << 16)         + p1 * __uint_as_float(q1.y << 16)
              + p2 * __uint_as_float(q2.y << 16)         + p3 * __uint_as_float(q3.y << 16);
        acc3 += p0 * __uint_as_float(q0.y & 0xffff0000u) + p1 * __uint_as_float(q1.y & 0xffff0000u)
              + p2 * __uint_as_float(q2.y & 0xffff0000u) + p3 * __uint_as_float(q3.y & 0xffff0000u);
    }
    for (; e < hi; ++e) {
        int s0 = ecsr[e];
        uint2 q0 = *(const uint2*)(h + (size_t)s0 * HC1 + hg * 64 + c0);
        float t0 = als[s0 * H1 + hg] + ad;
        t0 = (t0 > 0.f) ? t0 : SLOPE * t0;
        float p0 = __expf(t0);
        den += p0;
        acc0 += p0 * __uint_as_float(q0.x << 16);
        acc1 += p0 * __uint_as_float(q0.x & 0xffff0000u);
        acc2 += p0 * __uint_as_float(q0.y << 16);
        acc3 += p0 * __uint_as_float(q0.y & 0xffff0000u);
    }

    const bool f32in = (*flag != 0);
    const float inv = 1.f / den;
    float v0 = acc0 * inv + ldf(bias, hg * 64 + c0 + 0, f32in);
    float v1 = acc1 * inv + ldf(bias, hg * 64 + c0 + 1, f32in);
    float v2 = acc2 * inv + ldf(bias, hg * 64 + c0 + 2, f32in);
    float v3 = acc3 * inv + ldf(bias, hg * 64 + c0 + 3, f32in);
    v0 = (v0 > 0.f) ? v0 : (__expf(v0) - 1.f);
    v1 = (v1 > 0.f) ? v1 : (__expf(v1) - 1.f);
    v2 = (v2 > 0.f) ? v2 : (__expf(v2) - 1.f);
    v3 = (v3 > 0.f) ? v3 : (__expf(v3) - 1.f);
    uint2 st;
    st.x = (unsigned)f2bf(v0) | ((unsigned)f2bf(v1) << 16);
    st.y = (unsigned)f2bf(v2) | ((unsigned)f2bf(v3) << 16);
    *(uint2*)(out + (size_t)d * HC1 + hg * 64 + c0) = st;
}

// ---------------- fused softmax + gather-aggregate, layer 2 (H=1) ----------------
__global__ __launch_bounds__(256) void agg_node2(
    const int* __restrict__ rowptr, const int* __restrict__ ecsr,
    const unsigned short* __restrict__ h, const float* __restrict__ als,
    const float* __restrict__ ald, const void* __restrict__ bias,
    const unsigned* __restrict__ flag, float* __restrict__ out)
{
    int wave = (blockIdx.x * blockDim.x + threadIdx.x) >> 6;
    int lane = threadIdx.x & 63;
    if (wave >= N_NODES) return;
    const int d = wave;
    const int eg = lane >> 3;          // edge slot 0..7
    const int c0 = (lane & 7) << 3;    // channel base (8 channels)
    const int lo = rowptr[d], hi = rowptr[d + 1];
    const float ad = ald[d];

    float acc[8];
    #pragma unroll
    for (int j = 0; j < 8; ++j) acc[j] = 0.f;
    float den = 0.f;

    for (int eb = lo; eb < hi; eb += 8) {
        int e = eb + eg;
        if (e < hi) {
            int s = ecsr[e];
            uint4 q = *(const uint4*)(h + (size_t)s * OUT_CH + c0);
            float t = als[s] + ad;
            t = (t > 0.f) ? t : SLOPE * t;
            float p = __expf(t);
            den += p;
            acc[0] += p * __uint_as_float(q.x << 16);
            acc[1] += p * __uint_as_float(q.x & 0xffff0000u);
            acc[2] += p * __uint_as_float(q.y << 16);
            acc[3] += p * __uint_as_float(q.y & 0xffff0000u);
            acc[4] += p * __uint_as_float(q.z << 16);
            acc[5] += p * __uint_as_float(q.z & 0xffff0000u);
            acc[6] += p * __uint_as_float(q.w << 16);
            acc[7] += p * __uint_as_float(q.w & 0xffff0000u);
        }
    }
    #pragma unroll
    for (int off = 8; off <= 32; off <<= 1) {
        den += __shfl_xor(den, off, 64);
        #pragma unroll
        for (int j = 0; j < 8; ++j) acc[j] += __shfl_xor(acc[j], off, 64);
    }
    if (lane < 8) {
        const bool f32in = (*flag != 0);
        const float inv = 1.f / den;
        float4 v0, v1;
        v0.x = acc[0] * inv + ldf(bias, c0 + 0, f32in);
        v0.y = acc[1] * inv + ldf(bias, c0 + 1, f32in);
        v0.z = acc[2] * inv + ldf(bias, c0 + 2, f32in);
        v0.w = acc[3] * inv + ldf(bias, c0 + 3, f32in);
        v1.x = acc[4] * inv + ldf(bias, c0 + 4, f32in);
        v1.y = acc[5] * inv + ldf(bias, c0 + 5, f32in);
        v1.z = acc[6] * inv + ldf(bias, c0 + 6, f32in);
        v1.w = acc[7] * inv + ldf(bias, c0 + 7, f32in);
        *(float4*)(out + (size_t)d * OUT_CH + c0) = v0;
        *(float4*)(out + (size_t)d * OUT_CH + c0 + 4) = v1;
    }
}

extern "C" void kernel_launch(void* const* d_in, const int* in_sizes, int n_in,
                              void* d_out, int out_size, void* d_ws, size_t ws_size,
                              hipStream_t stream)
{
    const void* x   = d_in[0];
    const void* W1  = d_in[1];
    const void* as1 = d_in[2];
    const void* ad1 = d_in[3];
    const void* b1  = d_in[4];
    const void* W2  = d_in[5];
    const void* as2 = d_in[6];
    const void* ad2 = d_in[7];
    const void* b2  = d_in[8];
    const int* esrc = (const int*)d_in[9];
    const int* edst = (const int*)d_in[10];
    float* out = (float*)d_out;  // [N,64] float32

    char* base = (char*)d_ws;
    const size_t MB = 1024 * 1024;
    unsigned short* x16  = (unsigned short*)(base);            // 12.8 MB [N,128] bf16
    unsigned short* h16  = (unsigned short*)(base + 13 * MB);  // 25.6 MB h1 [N,256] bf16
    unsigned short* xo16 = (unsigned short*)(base + 39 * MB);  // 25.6 MB x2 [N,256] bf16
    unsigned short* h2   = (unsigned short*)(base + 65 * MB);  //  6.4 MB h2 [N,64] bf16
    float* als    = (float*)(base + 72 * MB);
    float* ald    = (float*)(base + 73 * MB);
    unsigned short* Wt1 = (unsigned short*)(base + 74 * MB);   // 64 KB [256][128]
    unsigned short* Wt2 = (unsigned short*)(base + 75 * MB);   // 32 KB [64][256]
    int* counts   = (int*)(base + 76 * MB);
    int* rowptr   = (int*)(base + 77 * MB);
    int* ecsr     = (int*)(base + 79 * MB);                    //  2.8 MB
    int* bsum     = (int*)(base + 82 * MB);                    //  196 ints
    int* boff     = bsum + 256;
    int* state    = boff + 256;                                //  2 ints
    unsigned* flag = (unsigned*)(base + 83 * MB);
    int* epos     = (int*)(base + 84 * MB);                    //  2.8 MB

    const int BLK = 256;
    const int node_wave_blocks = (N_NODES * 64 + BLK - 1) / BLK;  // 12500

    // 1. init: zero counts/state + detect dtype
    init_all<<<SCAN_NBLK + 1, BLK, 0, stream>>>(
        (const unsigned short*)x, flag, counts, state);

    // 2. conv (x16, Wt1, Wt2) || count edges (records per-edge slot in epos)
    conv_count<<<CONVB + EDGEB, BLK, 0, stream>>>(
        x, W1, W2, flag, x16, Wt1, Wt2, edst, counts, epos);

    // 3. single-dispatch scan -> rowptr
    scan_onepass<<<SCAN_NBLK, BLK, 0, stream>>>(
        counts, rowptr, bsum, boff, state);

    // 4. layer-1 GEMM || fill_csr (atomic-free)
    gemm1_fill<<<G1B + EDGEB, BLK, 0, stream>>>(
        x16, Wt1, as1, ad1, flag, h16, als, ald, esrc, edst, rowptr, epos, ecsr);

    // 5. layer-1 aggregate
    agg_node1<<<node_wave_blocks, BLK, 0, stream>>>(
        rowptr, ecsr, h16, als, ald, b1, flag, xo16);

    // 6. layer-2 GEMM
    gemm2<<<MT, BLK, 0, stream>>>(xo16, Wt2, as2, ad2, flag, h2, als, ald);

    // 7. layer-2 aggregate -> out
    agg_node2<<<node_wave_blocks, BLK, 0, stream>>>(
        rowptr, ecsr, h2, als, ald, b2, flag, out);
}